// Round 1
// baseline (335.193 us; speedup 1.0000x reference)
//
#include <hip/hip_runtime.h>
#include <hip/hip_bf16.h>

// Problem constants
#define BB 4
#define SS 2048
#define DD 1024
#define HH 16
#define HDD 64

typedef __attribute__((ext_vector_type(8))) short bf16x8;
typedef __attribute__((ext_vector_type(8))) unsigned short u16x8;
typedef __attribute__((ext_vector_type(4))) float f32x4;

#define GLD_LDS16(g, l) \
    __builtin_amdgcn_global_load_lds((const __attribute__((address_space(1))) void*)(g), \
                                     (__attribute__((address_space(3))) void*)(l), 16, 0, 0)

__device__ __forceinline__ unsigned short f32_to_bf16(float f) {
    unsigned int u = __float_as_uint(f);
    u += 0x7fffu + ((u >> 16) & 1u);   // RTNE
    return (unsigned short)(u >> 16);
}

// ---------------------------------------------------------------------------
// fp32 -> bf16 convert (vectorized, grid-stride)
// ---------------------------------------------------------------------------
__global__ __launch_bounds__(256) void convert_f32_bf16(
    const float* __restrict__ in, unsigned short* __restrict__ out, int n4) {
    int stride = gridDim.x * blockDim.x;
    for (int i = blockIdx.x * blockDim.x + threadIdx.x; i < n4; i += stride) {
        float4 v = ((const float4*)in)[i];
        ushort4 o;
        o.x = f32_to_bf16(v.x); o.y = f32_to_bf16(v.y);
        o.z = f32_to_bf16(v.z); o.w = f32_to_bf16(v.w);
        ((ushort4*)out)[i] = o;
    }
}

// ---------------------------------------------------------------------------
// Pack Wq/Wk/Wv [H][D][HD] fp32 -> WT [3*D][D] bf16 (B^T layout: row n = w*1024+h*64+e, col k = d)
// ---------------------------------------------------------------------------
__global__ __launch_bounds__(256) void pack_wqkv(
    const float* __restrict__ Wq, const float* __restrict__ Wk,
    const float* __restrict__ Wv, unsigned short* __restrict__ WT) {
    int bid = blockIdx.x;
    int w = bid >> 8, h = (bid >> 4) & 15, db = bid & 15;
    const float* src = (w == 0) ? Wq : ((w == 1) ? Wk : Wv);
    __shared__ float tile[64][68];
    int t = threadIdx.x;
    // read 64 d-rows x 64 e-cols, coalesced float4
    for (int p = t; p < 1024; p += 256) {
        int row = p >> 4, c4 = p & 15;
        float4 v = *(const float4*)(src + ((size_t)(h * 1024 + db * 64 + row)) * 64 + c4 * 4);
        tile[row][c4 * 4 + 0] = v.x; tile[row][c4 * 4 + 1] = v.y;
        tile[row][c4 * 4 + 2] = v.z; tile[row][c4 * 4 + 3] = v.w;
    }
    __syncthreads();
    size_t wbase = (size_t)w * 1024 * 1024;
    for (int p = t; p < 512; p += 256) {
        int e = p >> 3, c = p & 7;
        u16x8 pk;
#pragma unroll
        for (int j = 0; j < 8; ++j) pk[j] = f32_to_bf16(tile[c * 8 + j][e]);
        *(u16x8*)(WT + wbase + (size_t)(h * 64 + e) * 1024 + db * 64 + c * 8) = pk;
    }
}

// ---------------------------------------------------------------------------
// 128x128 tile bf16 GEMM, BK=64, 4 waves, global_load_lds + XOR-swizzled LDS.
// A: [M][1024] bf16 row-major.  Bm: [N][1024] bf16 (B^T: row n, col k).
// EPI 0: scatter C (bf16) into Q/K/V [B,H,S,HD].  EPI 1: C fp32 [M][1024].
// ---------------------------------------------------------------------------
template <int EPI>
__global__ __launch_bounds__(256) void gemm128(
    const unsigned short* __restrict__ A, const unsigned short* __restrict__ Bm,
    void* __restrict__ C0, void* __restrict__ C1, void* __restrict__ C2, int NBt) {
    __shared__ unsigned short As[128 * 64];
    __shared__ unsigned short Bs[128 * 64];
    int mb = blockIdx.x / NBt, nb = blockIdx.x % NBt;
    int tid = threadIdx.x;
    int lane = tid & 63, wid = tid >> 6;
    int wm = wid >> 1, wn = wid & 1;
    int g = lane >> 4, lr = lane & 15;
    int srow = lane >> 3, sch = lane & 7;          // staging: row-in-chunk, 16B-chunk-in-row
    int scol = (sch ^ srow) * 8;                   // pre-swizzled global k-offset (row&7 == srow)
    const int M0 = mb * 128, N0 = nb * 128;

    f32x4 acc[4][4] = {};

    for (int kt = 0; kt < 16; ++kt) {
        __syncthreads();  // previous compute done before overwriting LDS
#pragma unroll
        for (int i = 0; i < 4; ++i) {
            int c = wid * 4 + i;
            int row = c * 8 + srow;
            GLD_LDS16(A + (size_t)(M0 + row) * 1024 + kt * 64 + scol, As + c * 512);
            GLD_LDS16(Bm + (size_t)(N0 + row) * 1024 + kt * 64 + scol, Bs + c * 512);
        }
        __syncthreads();  // drains vmcnt: tiles ready
#pragma unroll
        for (int kk = 0; kk < 2; ++kk) {
            bf16x8 af[4], bf[4];
#pragma unroll
            for (int i = 0; i < 4; ++i) {
                int row = wm * 64 + i * 16 + lr;
                int ch = (kk * 4 + g) ^ (row & 7);
                af[i] = *(const bf16x8*)(As + row * 64 + ch * 8);
                int rowb = wn * 64 + i * 16 + lr;
                int chb = (kk * 4 + g) ^ (rowb & 7);
                bf[i] = *(const bf16x8*)(Bs + rowb * 64 + chb * 8);
            }
#pragma unroll
            for (int i = 0; i < 4; ++i)
#pragma unroll
                for (int j = 0; j < 4; ++j)
                    acc[i][j] = __builtin_amdgcn_mfma_f32_16x16x32_bf16(af[i], bf[j], acc[i][j], 0, 0, 0);
        }
    }

    if constexpr (EPI == 0) {
        unsigned short* Qo = (unsigned short*)C0;
        unsigned short* Ko = (unsigned short*)C1;
        unsigned short* Vo = (unsigned short*)C2;
#pragma unroll
        for (int i = 0; i < 4; ++i)
#pragma unroll
            for (int j = 0; j < 4; ++j)
#pragma unroll
                for (int r = 0; r < 4; ++r) {
                    int m = M0 + wm * 64 + i * 16 + g * 4 + r;
                    int n = N0 + wn * 64 + j * 16 + lr;
                    int b = m >> 11, s = m & 2047;
                    int w = n >> 10, h = (n >> 6) & 15, e = n & 63;
                    unsigned short* dst = (w == 0) ? Qo : ((w == 1) ? Ko : Vo);
                    dst[((size_t)(b * HH + h) * SS + s) * HDD + e] = f32_to_bf16(acc[i][j][r]);
                }
    } else {
        float* Co = (float*)C0;
#pragma unroll
        for (int i = 0; i < 4; ++i)
#pragma unroll
            for (int j = 0; j < 4; ++j)
#pragma unroll
                for (int r = 0; r < 4; ++r) {
                    int m = M0 + wm * 64 + i * 16 + g * 4 + r;
                    int n = N0 + wn * 64 + j * 16 + lr;
                    Co[(size_t)m * 1024 + n] = acc[i][j][r];
                }
    }
}

// ---------------------------------------------------------------------------
// V [B,H,S,HD] -> VT [B,H,HD,S]  (LDS tile transpose)
// ---------------------------------------------------------------------------
__global__ __launch_bounds__(256) void transpose_v(
    const unsigned short* __restrict__ V, unsigned short* __restrict__ VT) {
    int bh = blockIdx.x >> 5, sb = blockIdx.x & 31;
    __shared__ unsigned short tile[64][72];
    const unsigned short* src = V + ((size_t)bh * SS + sb * 64) * HDD;
    int t = threadIdx.x;
    for (int p = t; p < 512; p += 256) {
        int row = p >> 3, c = p & 7;
        *(u16x8*)&tile[row][c * 8] = *(const u16x8*)(src + row * 64 + c * 8);
    }
    __syncthreads();
    unsigned short* dst = VT + (size_t)bh * HDD * SS + sb * 64;
    for (int p = t; p < 512; p += 256) {
        int e = p >> 3, c = p & 7;
        u16x8 pk;
#pragma unroll
        for (int j = 0; j < 8; ++j) pk[j] = tile[c * 8 + j][e];
        *(u16x8*)(dst + (size_t)e * SS + c * 8) = pk;
    }
}

// ---------------------------------------------------------------------------
// Causal flash attention. Grid: B*H*(S/64). Block: 256 thr (4 waves x 16 q-rows).
// Q,K: [B,H,S,HD] bf16. VT: [B,H,HD,S] bf16. O: [B,S,H*HD] bf16 (GEMM-ready).
// ---------------------------------------------------------------------------
__global__ __launch_bounds__(256) void attn_fwd(
    const unsigned short* __restrict__ Q, const unsigned short* __restrict__ K,
    const unsigned short* __restrict__ VT, unsigned short* __restrict__ O) {
    const float LOG2E = 1.4426950408889634f;
    int bid = blockIdx.x;
    int bh = bid >> 5, qb = bid & 31;
    int b = bh >> 4, h = bh & 15;
    int tid = threadIdx.x, lane = tid & 63, w = tid >> 6;
    int g = lane >> 4, lr = lane & 15;
    int srow = lane >> 3, sch = lane & 7;
    int scol = (sch ^ srow) * 8;

    __shared__ unsigned short Ks[64 * 64];
    __shared__ unsigned short Vs[64 * 64];
    __shared__ unsigned short Ps[4][16 * 72];

    const unsigned short* Qp = Q + ((size_t)bh * SS + qb * 64) * HDD;
    const unsigned short* Kp = K + (size_t)bh * SS * HDD;
    const unsigned short* Vp = VT + (size_t)bh * HDD * SS;

    // Q fragments in registers (A-operand: row = lr within wave's 16 rows)
    bf16x8 qf[2];
    qf[0] = *(const bf16x8*)(Qp + (w * 16 + lr) * 64 + g * 8);
    qf[1] = *(const bf16x8*)(Qp + (w * 16 + lr) * 64 + 32 + g * 8);

    float m[4], l[4];
    f32x4 acc_o[4] = {};
#pragma unroll
    for (int r = 0; r < 4; ++r) { m[r] = -3.0e38f; l[r] = 0.f; }

    const int nt = qb + 1;
    for (int it = 0; it < nt; ++it) {
        int t0 = it * 64;
        __syncthreads();
#pragma unroll
        for (int i = 0; i < 2; ++i) {
            int c = w * 2 + i;
            int row = c * 8 + srow;
            GLD_LDS16(Kp + (size_t)(t0 + row) * HDD + scol, Ks + c * 512);
            GLD_LDS16(Vp + (size_t)row * SS + t0 + scol, Vs + c * 512);
        }
        __syncthreads();

        // S = Q K^T
        f32x4 sacc[4] = {};
#pragma unroll
        for (int kk = 0; kk < 2; ++kk)
#pragma unroll
            for (int ct = 0; ct < 4; ++ct) {
                int row = ct * 16 + lr;
                int ch = (kk * 4 + g) ^ (row & 7);
                bf16x8 kf = *(const bf16x8*)(Ks + row * 64 + ch * 8);
                sacc[ct] = __builtin_amdgcn_mfma_f32_16x16x32_bf16(qf[kk], kf, sacc[ct], 0, 0, 0);
            }

        // scale + causal mask (diagonal tile only)
        float sv[4][4];
        bool diag = (it == nt - 1);
#pragma unroll
        for (int ct = 0; ct < 4; ++ct)
#pragma unroll
            for (int r = 0; r < 4; ++r) {
                float xv = sacc[ct][r] * 0.125f;
                if (diag) {
                    int tt = t0 + ct * 16 + lr;
                    int qq = qb * 64 + w * 16 + g * 4 + r;
                    if (tt > qq) xv = -3.0e38f;
                }
                sv[ct][r] = xv;
            }

        // online softmax
        float sf[4];
#pragma unroll
        for (int r = 0; r < 4; ++r) {
            float tm = fmaxf(fmaxf(sv[0][r], sv[1][r]), fmaxf(sv[2][r], sv[3][r]));
            tm = fmaxf(tm, __shfl_xor(tm, 1, 16));
            tm = fmaxf(tm, __shfl_xor(tm, 2, 16));
            tm = fmaxf(tm, __shfl_xor(tm, 4, 16));
            tm = fmaxf(tm, __shfl_xor(tm, 8, 16));
            float nm = fmaxf(m[r], tm);
            sf[r] = exp2f((m[r] - nm) * LOG2E);
            m[r] = nm;
        }
        float rs[4] = {0.f, 0.f, 0.f, 0.f};
#pragma unroll
        for (int ct = 0; ct < 4; ++ct)
#pragma unroll
            for (int r = 0; r < 4; ++r) {
                float p = exp2f((sv[ct][r] - m[r]) * LOG2E);
                sv[ct][r] = p;
                rs[r] += p;
            }
#pragma unroll
        for (int r = 0; r < 4; ++r) {
            rs[r] += __shfl_xor(rs[r], 1, 16);
            rs[r] += __shfl_xor(rs[r], 2, 16);
            rs[r] += __shfl_xor(rs[r], 4, 16);
            rs[r] += __shfl_xor(rs[r], 8, 16);
            l[r] = l[r] * sf[r] + rs[r];
        }
#pragma unroll
        for (int ct = 0; ct < 4; ++ct)
#pragma unroll
            for (int r = 0; r < 4; ++r) acc_o[ct][r] *= sf[r];

        // P -> LDS (per-wave, re-layout for PV A-operand)
        unsigned short* pw = Ps[w];
#pragma unroll
        for (int ct = 0; ct < 4; ++ct)
#pragma unroll
            for (int r = 0; r < 4; ++r)
                pw[(g * 4 + r) * 72 + ct * 16 + lr] = f32_to_bf16(sv[ct][r]);

        bf16x8 pa[2];
        pa[0] = *(const bf16x8*)(pw + lr * 72 + g * 8);
        pa[1] = *(const bf16x8*)(pw + lr * 72 + 32 + g * 8);

        // O += P V
#pragma unroll
        for (int kk = 0; kk < 2; ++kk)
#pragma unroll
            for (int ct = 0; ct < 4; ++ct) {
                int row = ct * 16 + lr;
                int ch = (kk * 4 + g) ^ (row & 7);
                bf16x8 vf = *(const bf16x8*)(Vs + row * 64 + ch * 8);
                acc_o[ct] = __builtin_amdgcn_mfma_f32_16x16x32_bf16(pa[kk], vf, acc_o[ct], 0, 0, 0);
            }
    }

    // epilogue: normalize + store [B,S,H*HD]
#pragma unroll
    for (int r = 0; r < 4; ++r) l[r] = 1.0f / l[r];
#pragma unroll
    for (int ct = 0; ct < 4; ++ct)
#pragma unroll
        for (int r = 0; r < 4; ++r) {
            int s = qb * 64 + w * 16 + g * 4 + r;
            O[((size_t)(b * SS + s)) * DD + h * 64 + ct * 16 + lr] =
                f32_to_bf16(acc_o[ct][r] * l[r]);
        }
}

// ---------------------------------------------------------------------------
extern "C" void kernel_launch(void* const* d_in, const int* in_sizes, int n_in,
                              void* d_out, int out_size, void* d_ws, size_t ws_size,
                              hipStream_t stream) {
    (void)in_sizes; (void)n_in; (void)out_size; (void)ws_size;
    const float* x  = (const float*)d_in[0];
    const float* Wq = (const float*)d_in[1];
    const float* Wk = (const float*)d_in[2];
    const float* Wv = (const float*)d_in[3];
    const float* WO = (const float*)d_in[4];
    float* out = (float*)d_out;

    char* ws = (char*)d_ws;
    unsigned short* xb    = (unsigned short*)(ws + 0);          // 16 MB
    unsigned short* wqkvT = (unsigned short*)(ws + 16777216);   // 6 MB
    unsigned short* wob   = (unsigned short*)(ws + 23068672);   // 2 MB
    unsigned short* Qb    = (unsigned short*)(ws + 25165824);   // 16 MB
    unsigned short* Kb    = (unsigned short*)(ws + 41943040);   // 16 MB
    unsigned short* Vb    = (unsigned short*)(ws + 58720256);   // 16 MB
    unsigned short* VTb   = (unsigned short*)(ws + 75497472);   // 16 MB
    unsigned short* Ob    = (unsigned short*)(ws + 92274688);   // 16 MB

    convert_f32_bf16<<<2048, 256, 0, stream>>>(x, xb, (BB * SS * DD) / 4);
    convert_f32_bf16<<<1024, 256, 0, stream>>>(WO, wob, (DD * DD) / 4);
    pack_wqkv<<<768, 256, 0, stream>>>(Wq, Wk, Wv, wqkvT);
    gemm128<0><<<64 * 24, 256, 0, stream>>>(xb, wqkvT, (void*)Qb, (void*)Kb, (void*)Vb, 24);
    transpose_v<<<2048, 256, 0, stream>>>(Vb, VTb);
    attn_fwd<<<2048, 256, 0, stream>>>(Qb, Kb, VTb, Ob);
    gemm128<1><<<64 * 8, 256, 0, stream>>>(Ob, wob, (void*)out, nullptr, nullptr, 8);
}

// Round 2
// 254.237 us; speedup vs baseline: 1.3184x; 1.3184x over previous
//
#include <hip/hip_runtime.h>
#include <hip/hip_bf16.h>

// Problem constants
#define BB 4
#define SS 2048
#define DD 1024
#define HH 16
#define HDD 64

typedef __attribute__((ext_vector_type(8))) short bf16x8;
typedef __attribute__((ext_vector_type(8))) unsigned short u16x8;
typedef __attribute__((ext_vector_type(4))) float f32x4;

#define GLD_LDS16(g, l) \
    __builtin_amdgcn_global_load_lds((const __attribute__((address_space(1))) void*)(g), \
                                     (__attribute__((address_space(3))) void*)(l), 16, 0, 0)

__device__ __forceinline__ unsigned short f32_to_bf16(float f) {
    unsigned int u = __float_as_uint(f);
    u += 0x7fffu + ((u >> 16) & 1u);   // RTNE
    return (unsigned short)(u >> 16);
}

// ---------------------------------------------------------------------------
// fp32 -> bf16 convert (vectorized, grid-stride)
// ---------------------------------------------------------------------------
__global__ __launch_bounds__(256) void convert_f32_bf16(
    const float* __restrict__ in, unsigned short* __restrict__ out, int n4) {
    int stride = gridDim.x * blockDim.x;
    for (int i = blockIdx.x * blockDim.x + threadIdx.x; i < n4; i += stride) {
        float4 v = ((const float4*)in)[i];
        ushort4 o;
        o.x = f32_to_bf16(v.x); o.y = f32_to_bf16(v.y);
        o.z = f32_to_bf16(v.z); o.w = f32_to_bf16(v.w);
        ((ushort4*)out)[i] = o;
    }
}

// ---------------------------------------------------------------------------
// Pack Wq/Wk/Wv [H][D][HD] fp32 -> WT [3*D][D] bf16 (B^T layout)
// ---------------------------------------------------------------------------
__global__ __launch_bounds__(256) void pack_wqkv(
    const float* __restrict__ Wq, const float* __restrict__ Wk,
    const float* __restrict__ Wv, unsigned short* __restrict__ WT) {
    int bid = blockIdx.x;
    int w = bid >> 8, h = (bid >> 4) & 15, db = bid & 15;
    const float* src = (w == 0) ? Wq : ((w == 1) ? Wk : Wv);
    __shared__ float tile[64][68];
    int t = threadIdx.x;
    for (int p = t; p < 1024; p += 256) {
        int row = p >> 4, c4 = p & 15;
        float4 v = *(const float4*)(src + ((size_t)(h * 1024 + db * 64 + row)) * 64 + c4 * 4);
        tile[row][c4 * 4 + 0] = v.x; tile[row][c4 * 4 + 1] = v.y;
        tile[row][c4 * 4 + 2] = v.z; tile[row][c4 * 4 + 3] = v.w;
    }
    __syncthreads();
    size_t wbase = (size_t)w * 1024 * 1024;
    for (int p = t; p < 512; p += 256) {
        int e = p >> 3, c = p & 7;
        u16x8 pk;
#pragma unroll
        for (int j = 0; j < 8; ++j) pk[j] = f32_to_bf16(tile[c * 8 + j][e]);
        *(u16x8*)(WT + wbase + (size_t)(h * 64 + e) * 1024 + db * 64 + c * 8) = pk;
    }
}

// ---------------------------------------------------------------------------
// 128x128 tile bf16 GEMM, BK=64, 4 waves, global_load_lds + XOR-swizzled LDS.
// EPI 0: scatter C (bf16) into Q/K/V [B,H,S,HD]; Q pre-scaled by 0.125*log2e.
// EPI 1: C fp32 [M][1024].
// ---------------------------------------------------------------------------
template <int EPI>
__global__ __launch_bounds__(256) void gemm128(
    const unsigned short* __restrict__ A, const unsigned short* __restrict__ Bm,
    void* __restrict__ C0, void* __restrict__ C1, void* __restrict__ C2, int NBt) {
    __shared__ unsigned short As[128 * 64];
    __shared__ unsigned short Bs[128 * 64];
    int mb = blockIdx.x / NBt, nb = blockIdx.x % NBt;
    int tid = threadIdx.x;
    int lane = tid & 63, wid = tid >> 6;
    int wm = wid >> 1, wn = wid & 1;
    int g = lane >> 4, lr = lane & 15;
    int srow = lane >> 3, sch = lane & 7;
    int scol = (sch ^ srow) * 8;
    const int M0 = mb * 128, N0 = nb * 128;

    f32x4 acc[4][4] = {};

    for (int kt = 0; kt < 16; ++kt) {
        __syncthreads();
#pragma unroll
        for (int i = 0; i < 4; ++i) {
            int c = wid * 4 + i;
            int row = c * 8 + srow;
            GLD_LDS16(A + (size_t)(M0 + row) * 1024 + kt * 64 + scol, As + c * 512);
            GLD_LDS16(Bm + (size_t)(N0 + row) * 1024 + kt * 64 + scol, Bs + c * 512);
        }
        __syncthreads();
#pragma unroll
        for (int kk = 0; kk < 2; ++kk) {
            bf16x8 af[4], bfr[4];
#pragma unroll
            for (int i = 0; i < 4; ++i) {
                int row = wm * 64 + i * 16 + lr;
                int ch = (kk * 4 + g) ^ (row & 7);
                af[i] = *(const bf16x8*)(As + row * 64 + ch * 8);
                int rowb = wn * 64 + i * 16 + lr;
                int chb = (kk * 4 + g) ^ (rowb & 7);
                bfr[i] = *(const bf16x8*)(Bs + rowb * 64 + chb * 8);
            }
#pragma unroll
            for (int i = 0; i < 4; ++i)
#pragma unroll
                for (int j = 0; j < 4; ++j)
                    acc[i][j] = __builtin_amdgcn_mfma_f32_16x16x32_bf16(af[i], bfr[j], acc[i][j], 0, 0, 0);
        }
    }

    if constexpr (EPI == 0) {
        unsigned short* Qo = (unsigned short*)C0;
        unsigned short* Ko = (unsigned short*)C1;
        unsigned short* Vo = (unsigned short*)C2;
        const float QSCALE = 0.125f * 1.4426950408889634f;  // scale * log2(e)
#pragma unroll
        for (int i = 0; i < 4; ++i)
#pragma unroll
            for (int j = 0; j < 4; ++j)
#pragma unroll
                for (int r = 0; r < 4; ++r) {
                    int m = M0 + wm * 64 + i * 16 + g * 4 + r;
                    int n = N0 + wn * 64 + j * 16 + lr;
                    int b = m >> 11, s = m & 2047;
                    int w = n >> 10, h = (n >> 6) & 15, e = n & 63;
                    unsigned short* dst = (w == 0) ? Qo : ((w == 1) ? Ko : Vo);
                    float scl = (w == 0) ? QSCALE : 1.0f;
                    dst[((size_t)(b * HH + h) * SS + s) * HDD + e] = f32_to_bf16(acc[i][j][r] * scl);
                }
    } else {
        float* Co = (float*)C0;
#pragma unroll
        for (int i = 0; i < 4; ++i)
#pragma unroll
            for (int j = 0; j < 4; ++j)
#pragma unroll
                for (int r = 0; r < 4; ++r) {
                    int m = M0 + wm * 64 + i * 16 + g * 4 + r;
                    int n = N0 + wn * 64 + j * 16 + lr;
                    Co[(size_t)m * 1024 + n] = acc[i][j][r];
                }
    }
}

// ---------------------------------------------------------------------------
// V [B,H,S,HD] -> VT [B,H,HD,S]  (LDS tile transpose)
// ---------------------------------------------------------------------------
__global__ __launch_bounds__(256) void transpose_v(
    const unsigned short* __restrict__ V, unsigned short* __restrict__ VT) {
    int bh = blockIdx.x >> 5, sb = blockIdx.x & 31;
    __shared__ unsigned short tile[64][72];
    const unsigned short* src = V + ((size_t)bh * SS + sb * 64) * HDD;
    int t = threadIdx.x;
    for (int p = t; p < 512; p += 256) {
        int row = p >> 3, c = p & 7;
        *(u16x8*)&tile[row][c * 8] = *(const u16x8*)(src + row * 64 + c * 8);
    }
    __syncthreads();
    unsigned short* dst = VT + (size_t)bh * HDD * SS + sb * 64;
    for (int p = t; p < 512; p += 256) {
        int e = p >> 3, c = p & 7;
        u16x8 pk;
#pragma unroll
        for (int j = 0; j < 8; ++j) pk[j] = tile[c * 8 + j][e];
        *(u16x8*)(dst + (size_t)e * SS + c * 8) = pk;
    }
}

// ---------------------------------------------------------------------------
// Causal flash attention v2.
// Grid: 64 bh * 16 qb (qb reversed: longest-first). Block: 256 thr, 4 waves.
// QBLK=128 (wave owns 32 q-rows), KVBLK=64, double-buffered K/V staging.
// Q pre-scaled by 0.125*log2e -> softmax in exp2 domain.
// Q,K: [B,H,S,HD] bf16. VT: [B,H,HD,S] bf16. O: [B,S,D] bf16.
// ---------------------------------------------------------------------------
__global__ __launch_bounds__(256) void attn_fwd(
    const unsigned short* __restrict__ Q, const unsigned short* __restrict__ K,
    const unsigned short* __restrict__ VT, unsigned short* __restrict__ O) {
    int bid = blockIdx.x;
    int qb = 15 - (bid >> 6);          // heaviest q-blocks first
    int bh = bid & 63;
    int b = bh >> 4, h = bh & 15;
    int tid = threadIdx.x, lane = tid & 63, w = tid >> 6;
    int g = lane >> 4, lr = lane & 15;
    int srow = lane >> 3, sch = lane & 7;
    int scol = (sch ^ srow) * 8;       // pre-swizzled global k-offset

    __shared__ unsigned short Ks[2][64 * 64];
    __shared__ unsigned short Vs[2][64 * 64];
    __shared__ unsigned short Ps[4][32 * 72];

    const int q0 = qb * 128;
    const unsigned short* Qp = Q + ((size_t)bh * SS + q0 + w * 32) * HDD;
    const unsigned short* Kp = K + (size_t)bh * SS * HDD;
    const unsigned short* Vp = VT + (size_t)bh * HDD * SS;

    // Q fragments in registers: wave owns rows [w*32, w*32+32) as 2 groups of 16
    bf16x8 qf[2][2];
#pragma unroll
    for (int rg = 0; rg < 2; ++rg) {
        qf[rg][0] = *(const bf16x8*)(Qp + (rg * 16 + lr) * 64 + g * 8);
        qf[rg][1] = *(const bf16x8*)(Qp + (rg * 16 + lr) * 64 + 32 + g * 8);
    }

    float m[2][4], l[2][4];
    f32x4 acc_o[2][4] = {};
#pragma unroll
    for (int rg = 0; rg < 2; ++rg)
#pragma unroll
        for (int r = 0; r < 4; ++r) { m[rg][r] = -3.0e38f; l[rg][r] = 0.f; }

    const int nt = 2 * qb + 2;

    // prologue: stage tile 0 into buffer 0
#pragma unroll
    for (int i = 0; i < 2; ++i) {
        int c = w * 2 + i;
        int row = c * 8 + srow;
        GLD_LDS16(Kp + (size_t)row * HDD + scol, Ks[0] + c * 512);
        GLD_LDS16(Vp + (size_t)row * SS + scol, Vs[0] + c * 512);
    }
    __syncthreads();

    for (int it = 0; it < nt; ++it) {
        int cur = it & 1;
        // issue next tile's loads early (into the other buffer)
        if (it + 1 < nt) {
            int t1 = (it + 1) * 64;
#pragma unroll
            for (int i = 0; i < 2; ++i) {
                int c = w * 2 + i;
                int row = c * 8 + srow;
                GLD_LDS16(Kp + (size_t)(t1 + row) * HDD + scol, Ks[cur ^ 1] + c * 512);
                GLD_LDS16(Vp + (size_t)row * SS + t1 + scol, Vs[cur ^ 1] + c * 512);
            }
        }
        int t0 = it * 64;

        // S = Q K^T  (values already in log2 domain via Q pre-scale)
        f32x4 sacc[2][4] = {};
#pragma unroll
        for (int kk = 0; kk < 2; ++kk)
#pragma unroll
            for (int ct = 0; ct < 4; ++ct) {
                int row = ct * 16 + lr;
                int ch = (kk * 4 + g) ^ (row & 7);
                bf16x8 kf = *(const bf16x8*)(Ks[cur] + row * 64 + ch * 8);
#pragma unroll
                for (int rg = 0; rg < 2; ++rg)
                    sacc[rg][ct] = __builtin_amdgcn_mfma_f32_16x16x32_bf16(qf[rg][kk], kf, sacc[rg][ct], 0, 0, 0);
            }

        // causal mask (last two tiles only)
        bool diag = (it >= nt - 2);
        if (diag) {
#pragma unroll
            for (int rg = 0; rg < 2; ++rg)
#pragma unroll
                for (int ct = 0; ct < 4; ++ct)
#pragma unroll
                    for (int r = 0; r < 4; ++r) {
                        int tt = t0 + ct * 16 + lr;
                        int qq = q0 + w * 32 + rg * 16 + g * 4 + r;
                        if (tt > qq) sacc[rg][ct][r] = -3.0e38f;
                    }
        }

        // online softmax (exp2 domain)
        float sf[2][4];
#pragma unroll
        for (int rg = 0; rg < 2; ++rg)
#pragma unroll
            for (int r = 0; r < 4; ++r) {
                float tm = fmaxf(fmaxf(sacc[rg][0][r], sacc[rg][1][r]),
                                 fmaxf(sacc[rg][2][r], sacc[rg][3][r]));
                tm = fmaxf(tm, __shfl_xor(tm, 1, 16));
                tm = fmaxf(tm, __shfl_xor(tm, 2, 16));
                tm = fmaxf(tm, __shfl_xor(tm, 4, 16));
                tm = fmaxf(tm, __shfl_xor(tm, 8, 16));
                float nm = fmaxf(m[rg][r], tm);
                sf[rg][r] = exp2f(m[rg][r] - nm);
                m[rg][r] = nm;
            }
        float rs[2][4] = {};
#pragma unroll
        for (int rg = 0; rg < 2; ++rg)
#pragma unroll
            for (int ct = 0; ct < 4; ++ct)
#pragma unroll
                for (int r = 0; r < 4; ++r) {
                    float p = exp2f(sacc[rg][ct][r] - m[rg][r]);
                    sacc[rg][ct][r] = p;
                    rs[rg][r] += p;
                }
#pragma unroll
        for (int rg = 0; rg < 2; ++rg)
#pragma unroll
            for (int r = 0; r < 4; ++r) {
                float s = rs[rg][r];
                s += __shfl_xor(s, 1, 16);
                s += __shfl_xor(s, 2, 16);
                s += __shfl_xor(s, 4, 16);
                s += __shfl_xor(s, 8, 16);
                l[rg][r] = l[rg][r] * sf[rg][r] + s;
            }
#pragma unroll
        for (int rg = 0; rg < 2; ++rg)
#pragma unroll
            for (int ct = 0; ct < 4; ++ct)
#pragma unroll
                for (int r = 0; r < 4; ++r) acc_o[rg][ct][r] *= sf[rg][r];

        // P -> LDS (per-wave re-layout for PV A-operand)
        unsigned short* pw = Ps[w];
#pragma unroll
        for (int rg = 0; rg < 2; ++rg)
#pragma unroll
            for (int ct = 0; ct < 4; ++ct)
#pragma unroll
                for (int r = 0; r < 4; ++r)
                    pw[(rg * 16 + g * 4 + r) * 72 + ct * 16 + lr] = f32_to_bf16(sacc[rg][ct][r]);

        bf16x8 pa[2][2];
#pragma unroll
        for (int rg = 0; rg < 2; ++rg) {
            pa[rg][0] = *(const bf16x8*)(pw + (rg * 16 + lr) * 72 + g * 8);
            pa[rg][1] = *(const bf16x8*)(pw + (rg * 16 + lr) * 72 + 32 + g * 8);
        }

        // O += P V
#pragma unroll
        for (int kk = 0; kk < 2; ++kk)
#pragma unroll
            for (int ct = 0; ct < 4; ++ct) {
                int row = ct * 16 + lr;
                int ch = (kk * 4 + g) ^ (row & 7);
                bf16x8 vf = *(const bf16x8*)(Vs[cur] + row * 64 + ch * 8);
#pragma unroll
                for (int rg = 0; rg < 2; ++rg)
                    acc_o[rg][ct] = __builtin_amdgcn_mfma_f32_16x16x32_bf16(pa[rg][kk], vf, acc_o[rg][ct], 0, 0, 0);
            }

        __syncthreads();  // next tile staged + everyone done with cur
    }

    // epilogue: normalize + store [B,S,D]
#pragma unroll
    for (int rg = 0; rg < 2; ++rg)
#pragma unroll
        for (int r = 0; r < 4; ++r) l[rg][r] = 1.0f / l[rg][r];
#pragma unroll
    for (int rg = 0; rg < 2; ++rg)
#pragma unroll
        for (int ct = 0; ct < 4; ++ct)
#pragma unroll
            for (int r = 0; r < 4; ++r) {
                int s = q0 + w * 32 + rg * 16 + g * 4 + r;
                O[((size_t)(b * SS + s)) * DD + h * 64 + ct * 16 + lr] =
                    f32_to_bf16(acc_o[rg][ct][r] * l[rg][r]);
            }
}

// ---------------------------------------------------------------------------
extern "C" void kernel_launch(void* const* d_in, const int* in_sizes, int n_in,
                              void* d_out, int out_size, void* d_ws, size_t ws_size,
                              hipStream_t stream) {
    (void)in_sizes; (void)n_in; (void)out_size; (void)ws_size;
    const float* x  = (const float*)d_in[0];
    const float* Wq = (const float*)d_in[1];
    const float* Wk = (const float*)d_in[2];
    const float* Wv = (const float*)d_in[3];
    const float* WO = (const float*)d_in[4];
    float* out = (float*)d_out;

    char* ws = (char*)d_ws;
    unsigned short* xb    = (unsigned short*)(ws + 0);          // 16 MB
    unsigned short* wqkvT = (unsigned short*)(ws + 16777216);   // 6 MB
    unsigned short* wob   = (unsigned short*)(ws + 23068672);   // 2 MB
    unsigned short* Qb    = (unsigned short*)(ws + 25165824);   // 16 MB
    unsigned short* Kb    = (unsigned short*)(ws + 41943040);   // 16 MB
    unsigned short* Vb    = (unsigned short*)(ws + 58720256);   // 16 MB
    unsigned short* VTb   = (unsigned short*)(ws + 75497472);   // 16 MB
    unsigned short* Ob    = (unsigned short*)(ws + 92274688);   // 16 MB

    convert_f32_bf16<<<2048, 256, 0, stream>>>(x, xb, (BB * SS * DD) / 4);
    convert_f32_bf16<<<1024, 256, 0, stream>>>(WO, wob, (DD * DD) / 4);
    pack_wqkv<<<768, 256, 0, stream>>>(Wq, Wk, Wv, wqkvT);
    gemm128<0><<<64 * 24, 256, 0, stream>>>(xb, wqkvT, (void*)Qb, (void*)Kb, (void*)Vb, 24);
    transpose_v<<<2048, 256, 0, stream>>>(Vb, VTb);
    attn_fwd<<<1024, 256, 0, stream>>>(Qb, Kb, VTb, Ob);
    gemm128<1><<<64 * 8, 256, 0, stream>>>(Ob, wob, (void*)out, nullptr, nullptr, 8);
}